// Round 5
// baseline (71.848 us; speedup 1.0000x reference)
//
#include <hip/hip_runtime.h>

typedef __attribute__((ext_vector_type(8))) _Float16 half8;
typedef __attribute__((ext_vector_type(4))) _Float16 half4;
typedef __attribute__((ext_vector_type(4))) float f32x4;
#if __has_builtin(__builtin_amdgcn_cvt_pkrtz)
typedef __attribute__((ext_vector_type(2))) __fp16 fp16x2;
#endif

#define ALPHA 0.2f
#define LOG2E 1.44269504f

__device__ __forceinline__ void gload_lds16(const void* g, void* l) {
  __builtin_amdgcn_global_load_lds((const __attribute__((address_space(1))) unsigned int*)g,
                                   (__attribute__((address_space(3))) unsigned int*)l, 16, 0, 0);
}

__device__ __forceinline__ float fexp2(float x) {
#if __has_builtin(__builtin_amdgcn_exp2f)
  return __builtin_amdgcn_exp2f(x);
#else
  return exp2f(x);
#endif
}

// ---------------- K0a: W fp32 -> fp16, PRE-SWIZZLED (unit8 XOR (n&7)) ----------------
__global__ __launch_bounds__(256) void k_convW(const float* __restrict__ W,
                                               _Float16* __restrict__ W16) {
  int idx4 = blockIdx.x * 256 + threadIdx.x;  // half4 unit
  int n = idx4 >> 7;                          // row 0..255
  int q = idx4 & 127;                         // half4 within row
  float4 v = *reinterpret_cast<const float4*>(W + n * 512 + q * 4);
  half4 hv = {(_Float16)v.x, (_Float16)v.y, (_Float16)v.z, (_Float16)v.w};
  int kp = (q * 4) ^ ((n & 7) << 3);          // swizzle within 64-elem blocks
  *reinterpret_cast<half4*>(W16 + n * 512 + kp) = hv;
}

// ---------------- K0b: u = W^T a  (8 blocks, coalesced over k) ----------------
__global__ __launch_bounds__(256) void k_uvec(const float* __restrict__ W,
                                              const float* __restrict__ a1,
                                              const float* __restrict__ a2,
                                              float* __restrict__ u1,
                                              float* __restrict__ u2) {
  __shared__ float p1[4][64], p2[4][64];
  int t = threadIdx.x;
  int l = t & 63, g = t >> 6;
  int k = blockIdx.x * 64 + l;
  float x1 = 0.f, x2 = 0.f;
  for (int o = g * 64; o < g * 64 + 64; ++o) {
    float wv = W[o * 512 + k];
    x1 += wv * a1[o];
    x2 += wv * a2[o];
  }
  p1[g][l] = x1; p2[g][l] = x2;
  __syncthreads();
  if (g == 0) {
    u1[k] = p1[0][l] + p1[1][l] + p1[2][l] + p1[3][l];
    u2[k] = p2[0][l] + p2[1][l] + p2[2][l] + p2[3][l];
  }
}

// ---------------- K2: Wh GEMM + fused s1/s2, counted-vmcnt pipeline ----------------
// grid 256, 512 thr (8 waves = 2 rg x 4 cg); block = 64 rows x 256 cols; wave 32x64.
// B (W16) triple-buffered via global_load_lds; A reg-staged fp32->fp16, dbuf.
__global__ __launch_bounds__(512) void k_gemm_wh(const float* __restrict__ h,
                                                 const _Float16* __restrict__ W16,
                                                 const float* __restrict__ u1,
                                                 const float* __restrict__ u2,
                                                 float* __restrict__ s1o,
                                                 float* __restrict__ s2o,
                                                 _Float16* __restrict__ WhT) {
  __shared__ _Float16 Ab[2][64 * 64];    // 8 KB each, XOR-swizzled
  __shared__ _Float16 Bb[3][256 * 64];   // 32 KB each, linear copy of pre-swizzled W16
  __shared__ float u_lds[1024];          // u1[0..511], u2[512..1023]
  const int t = threadIdx.x, lane = t & 63, w = t >> 6;
  const int rg = w >> 2, cg = w & 3;
  const int i0 = blockIdx.x * 64;        // global row 0..16383
  const int b = i0 >> 11, n0 = i0 & 2047;
  const int ar = t >> 3, au = t & 7;     // A-stage: row 0..63, 8-float chunk 0..7
  const int arow = lane & 15;
  const float* hrow = h + (size_t)(i0 + ar) * 512 + au * 8;
  const int awoff = ar * 128 + ((au * 16) ^ ((ar & 7) << 4));

  // stage u to LDS (keeps the main loop free of VMEM register consumers)
  u_lds[t] = u1[t];
  u_lds[512 + t] = u2[t];
  __syncthreads();  // full drain: clean vmcnt slate

  f32x4 acc[2][4];
#pragma unroll
  for (int mi = 0; mi < 2; ++mi)
#pragma unroll
    for (int ni = 0; ni < 4; ++ni) acc[mi][ni] = (f32x4){0.f, 0.f, 0.f, 0.f};
  float x1 = 0.f, x2 = 0.f;

  float4 aRx[2], aRy[2];
  // prologue: A(0) regs, B(0)/B(1) issue, A(1) regs, write A(0)
  aRx[0] = *reinterpret_cast<const float4*>(hrow);
  aRy[0] = *reinterpret_cast<const float4*>(hrow + 4);
#pragma unroll
  for (int x = 0; x < 2; ++x)
#pragma unroll
    for (int q = 0; q < 4; ++q) {
      int idx = q * 512 + t;
      int cl = idx >> 3, uu = idx & 7;
      gload_lds16(W16 + cl * 512 + x * 64 + uu * 8, (char*)&Bb[x][0] + idx * 16);
    }
  aRx[1] = *reinterpret_cast<const float4*>(hrow + 64);
  aRy[1] = *reinterpret_cast<const float4*>(hrow + 68);
  {  // write A(0) + fused u-FMA(0)
    float4 a0 = aRx[0], a1v = aRy[0];
    half8 av;
    av[0] = (_Float16)a0.x; av[1] = (_Float16)a0.y; av[2] = (_Float16)a0.z; av[3] = (_Float16)a0.w;
    av[4] = (_Float16)a1v.x; av[5] = (_Float16)a1v.y; av[6] = (_Float16)a1v.z; av[7] = (_Float16)a1v.w;
    *reinterpret_cast<half8*>((char*)&Ab[0][0] + awoff) = av;
    const float* up1 = &u_lds[au * 8];
    const float* up2 = &u_lds[512 + au * 8];
    x1 += a0.x * up1[0] + a0.y * up1[1] + a0.z * up1[2] + a0.w * up1[3]
        + a1v.x * up1[4] + a1v.y * up1[5] + a1v.z * up1[6] + a1v.w * up1[7];
    x2 += a0.x * up2[0] + a0.y * up2[1] + a0.z * up2[2] + a0.w * up2[3]
        + a1v.x * up2[4] + a1v.y * up2[5] + a1v.z * up2[6] + a1v.w * up2[7];
  }

#pragma unroll
  for (int kt = 0; kt < 8; ++kt) {
    asm volatile("s_waitcnt vmcnt(6) lgkmcnt(0)" ::: "memory");
    __builtin_amdgcn_s_barrier();
    if (kt < 6) {  // issue B(kt+2)
      const int k0 = (kt + 2) * 64;
      const int p = (kt + 2) % 3;
#pragma unroll
      for (int q = 0; q < 4; ++q) {
        int idx = q * 512 + t;
        int cl = idx >> 3, uu = idx & 7;
        gload_lds16(W16 + cl * 512 + k0 + uu * 8, (char*)&Bb[p][0] + idx * 16);
      }
      // load A(kt+2) regs (overwrites consumed set)
      aRx[kt & 1] = *reinterpret_cast<const float4*>(hrow + k0);
      aRy[kt & 1] = *reinterpret_cast<const float4*>(hrow + k0 + 4);
    }
    if (kt < 7) {  // write A(kt+1) + fused u-FMA(kt+1)
      float4 a0 = aRx[(kt + 1) & 1], a1v = aRy[(kt + 1) & 1];
      half8 av;
      av[0] = (_Float16)a0.x; av[1] = (_Float16)a0.y; av[2] = (_Float16)a0.z; av[3] = (_Float16)a0.w;
      av[4] = (_Float16)a1v.x; av[5] = (_Float16)a1v.y; av[6] = (_Float16)a1v.z; av[7] = (_Float16)a1v.w;
      *reinterpret_cast<half8*>((char*)&Ab[(kt + 1) & 1][0] + awoff) = av;
      const float* up1 = &u_lds[(kt + 1) * 64 + au * 8];
      const float* up2 = &u_lds[512 + (kt + 1) * 64 + au * 8];
      x1 += a0.x * up1[0] + a0.y * up1[1] + a0.z * up1[2] + a0.w * up1[3]
          + a1v.x * up1[4] + a1v.y * up1[5] + a1v.z * up1[6] + a1v.w * up1[7];
      x2 += a0.x * up2[0] + a0.y * up2[1] + a0.z * up2[2] + a0.w * up2[3]
          + a1v.x * up2[4] + a1v.y * up2[5] + a1v.z * up2[6] + a1v.w * up2[7];
    }
    // compute tile kt
    const char* Ac = (const char*)&Ab[kt & 1][0];
    const char* Bc = (const char*)&Bb[kt % 3][0];
#pragma unroll
    for (int kk = 0; kk < 2; ++kk) {
      const int jb = ((lane >> 4) * 8 + kk * 32) * 2;
      half8 afr[2];
#pragma unroll
      for (int mi = 0; mi < 2; ++mi) {
        int rr = rg * 32 + 16 * mi + arow;
        afr[mi] = *reinterpret_cast<const half8*>(Ac + rr * 128 + (jb ^ ((rr & 7) << 4)));
      }
#pragma unroll
      for (int ni = 0; ni < 4; ++ni) {
        int nn = cg * 64 + 16 * ni + arow;
        half8 bfr = *reinterpret_cast<const half8*>(Bc + nn * 128 + (jb ^ ((nn & 7) << 4)));
#pragma unroll
        for (int mi = 0; mi < 2; ++mi)
          acc[mi][ni] = __builtin_amdgcn_mfma_f32_16x16x32_f16(afr[mi], bfr, acc[mi][ni], 0, 0, 0);
      }
    }
  }
  // s1/s2: reduce over the 8 lanes sharing a row
  x1 += __shfl_xor(x1, 1); x1 += __shfl_xor(x1, 2); x1 += __shfl_xor(x1, 4);
  x2 += __shfl_xor(x2, 1); x2 += __shfl_xor(x2, 2); x2 += __shfl_xor(x2, 4);
  if (au == 0) { s1o[i0 + ar] = x1; s2o[i0 + ar] = x2; }
  // epilogue: pre-swizzled WhT store (unit8 XOR (c&7), within 64-n blocks)
  _Float16* whtb = WhT + (size_t)b * 256 * 2048;
#pragma unroll
  for (int mi = 0; mi < 2; ++mi)
#pragma unroll
    for (int ni = 0; ni < 4; ++ni) {
      int c = cg * 64 + 16 * ni + arow;
      int nb = n0 + rg * 32 + 16 * mi + (lane >> 4) * 4;
      int np = nb ^ ((c & 7) << 3);
      f32x4 a = acc[mi][ni];
      half4 hv = {(_Float16)a[0], (_Float16)a[1], (_Float16)a[2], (_Float16)a[3]};
      *reinterpret_cast<half4*>(whtb + (size_t)c * 2048 + np) = hv;
    }
}

// ---------------- K3: fused softmax(P) @ Wh + ELU, counted-vmcnt pipeline ----------------
// grid 256 (bid&7 = batch -> XCD affinity; bid>>3 = 64-row block), 1024 thr (16 waves
// = 4 rg x 4 cg, wave 16 rows x 64 cols). B triple-buffered (32 KB tiles), P dbuf,
// s2 staged+scaled in LDS, per-batch max computed in-block (k_smax deleted).
__global__ __launch_bounds__(1024) void k_attn(const _Float16* __restrict__ WhT,
                                               const float* __restrict__ s1,
                                               const float* __restrict__ s2,
                                               float* __restrict__ out) {
  __shared__ _Float16 Bb[3][256 * 64];  // 32 KB each
  __shared__ _Float16 Pb[2][64 * 64];   // 8 KB each
  __shared__ float s2s[2048];
  __shared__ float red[16];
  __shared__ float d_lds[64];
  const int t = threadIdx.x, lane = t & 63, w = t >> 6;
  const int rg = w >> 2, cg = w & 3;
  const int b = blockIdx.x & 7;
  const int i0 = (blockIdx.x >> 3) * 64;
  const _Float16* whtb = WhT + (size_t)b * 256 * 2048;
  const int arow = lane & 15;
  const int pr = t >> 4, pj = t & 15;  // P-build: row 0..63, 4-j chunk
  const float s1v = s1[b * 2048 + i0 + pr];

  // stage s2 (scaled by log2e) + block-wide max
  float2 sv2 = *reinterpret_cast<const float2*>(s2 + b * 2048 + t * 2);
  float m0 = fmaxf(sv2.x, sv2.y);
  *reinterpret_cast<float2*>(&s2s[t * 2]) = make_float2(sv2.x * LOG2E, sv2.y * LOG2E);
#pragma unroll
  for (int off = 32; off >= 1; off >>= 1) m0 = fmaxf(m0, __shfl_xor(m0, off));
  if (lane == 0) red[w] = m0;
  __syncthreads();  // full drain: clean vmcnt slate; s2s/red visible
  float smaxL;
  {
    float mm = red[0];
#pragma unroll
    for (int i = 1; i < 16; ++i) mm = fmaxf(mm, red[i]);
    smaxL = mm * LOG2E;
  }
  const float s1L = LOG2E * s1v;
  const float e0L = s1L + smaxL;
  const float mrowL = fmaxf(e0L, ALPHA * e0L);  // closed-form row max (LR monotonic)
  const float C1 = s1L - mrowL;
  const float C2 = fmaf(ALPHA, s1L, -mrowL);
  const int pwoff = pr * 128 + ((pj * 8) ^ ((pr & 7) << 4));
  half8 onesb;
  {
    _Float16 ov = (arow == 0) ? (_Float16)1.0f : (_Float16)0.0f;
#pragma unroll
    for (int x = 0; x < 8; ++x) onesb[x] = ov;
  }
  f32x4 acc[4];
#pragma unroll
  for (int ni = 0; ni < 4; ++ni) acc[ni] = (f32x4){0.f, 0.f, 0.f, 0.f};
  f32x4 accd = (f32x4){0.f, 0.f, 0.f, 0.f};

  // build P(0)
  {
    float4 sv = *reinterpret_cast<const float4*>(&s2s[pj * 4]);
    float p0 = fexp2(fmaxf(C1 + sv.x, fmaf(ALPHA, sv.x, C2)));
    float p1 = fexp2(fmaxf(C1 + sv.y, fmaf(ALPHA, sv.y, C2)));
    float p2 = fexp2(fmaxf(C1 + sv.z, fmaf(ALPHA, sv.z, C2)));
    float p3 = fexp2(fmaxf(C1 + sv.w, fmaf(ALPHA, sv.w, C2)));
    half4 hv;
#if __has_builtin(__builtin_amdgcn_cvt_pkrtz)
    fp16x2 q0 = __builtin_amdgcn_cvt_pkrtz(p0, p1);
    fp16x2 q1 = __builtin_amdgcn_cvt_pkrtz(p2, p3);
    hv[0] = (_Float16)q0[0]; hv[1] = (_Float16)q0[1];
    hv[2] = (_Float16)q1[0]; hv[3] = (_Float16)q1[1];
#else
    hv[0] = (_Float16)p0; hv[1] = (_Float16)p1; hv[2] = (_Float16)p2; hv[3] = (_Float16)p3;
#endif
    *reinterpret_cast<half4*>((char*)&Pb[0][0] + pwoff) = hv;
  }
  // issue B(0), B(1): 2 gload_lds per thread per tile
#pragma unroll
  for (int x = 0; x < 2; ++x)
#pragma unroll
    for (int q = 0; q < 2; ++q) {
      int idx = q * 1024 + t;
      int cl = idx >> 3, uu = idx & 7;
      gload_lds16(whtb + (size_t)cl * 2048 + x * 64 + uu * 8, (char*)&Bb[x][0] + idx * 16);
    }

  for (int jt = 0; jt < 32; ++jt) {
    // B(jt) landed (own 2 loads beyond the 2 in flight for jt+1); P writes visible
    if (jt < 31) asm volatile("s_waitcnt vmcnt(2) lgkmcnt(0)" ::: "memory");
    else         asm volatile("s_waitcnt vmcnt(0) lgkmcnt(0)" ::: "memory");
    __builtin_amdgcn_s_barrier();
    if (jt < 30) {  // issue B(jt+2)
      const int j0n = (jt + 2) * 64;
      const int p = (jt + 2) % 3;
#pragma unroll
      for (int q = 0; q < 2; ++q) {
        int idx = q * 1024 + t;
        int cl = idx >> 3, uu = idx & 7;
        gload_lds16(whtb + (size_t)cl * 2048 + j0n + uu * 8, (char*)&Bb[p][0] + idx * 16);
      }
    }
    if (jt < 31) {  // build P(jt+1)
      float4 sv = *reinterpret_cast<const float4*>(&s2s[(jt + 1) * 64 + pj * 4]);
      float p0 = fexp2(fmaxf(C1 + sv.x, fmaf(ALPHA, sv.x, C2)));
      float p1 = fexp2(fmaxf(C1 + sv.y, fmaf(ALPHA, sv.y, C2)));
      float p2 = fexp2(fmaxf(C1 + sv.z, fmaf(ALPHA, sv.z, C2)));
      float p3 = fexp2(fmaxf(C1 + sv.w, fmaf(ALPHA, sv.w, C2)));
      half4 hv;
#if __has_builtin(__builtin_amdgcn_cvt_pkrtz)
      fp16x2 q0 = __builtin_amdgcn_cvt_pkrtz(p0, p1);
      fp16x2 q1 = __builtin_amdgcn_cvt_pkrtz(p2, p3);
      hv[0] = (_Float16)q0[0]; hv[1] = (_Float16)q0[1];
      hv[2] = (_Float16)q1[0]; hv[3] = (_Float16)q1[1];
#else
      hv[0] = (_Float16)p0; hv[1] = (_Float16)p1; hv[2] = (_Float16)p2; hv[3] = (_Float16)p3;
#endif
      *reinterpret_cast<half4*>((char*)&Pb[(jt + 1) & 1][0] + pwoff) = hv;
    }
    // compute tile jt
    const char* Bc = (const char*)&Bb[jt % 3][0];
    const char* Pc = (const char*)&Pb[jt & 1][0];
#pragma unroll
    for (int kk = 0; kk < 2; ++kk) {
      const int jb = ((lane >> 4) * 8 + kk * 32) * 2;
      const int ar64 = rg * 16 + arow;
      half8 afr = *reinterpret_cast<const half8*>(Pc + ar64 * 128 + (jb ^ ((ar64 & 7) << 4)));
      if (cg == 0)  // denominator: ones-column MFMA (row-sums of fp16 P)
        accd = __builtin_amdgcn_mfma_f32_16x16x32_f16(afr, onesb, accd, 0, 0, 0);
#pragma unroll
      for (int ni = 0; ni < 4; ++ni) {
        int cl = cg * 64 + 16 * ni + arow;
        half8 bfr = *reinterpret_cast<const half8*>(Bc + cl * 128 + (jb ^ ((cl & 7) << 4)));
        acc[ni] = __builtin_amdgcn_mfma_f32_16x16x32_f16(afr, bfr, acc[ni], 0, 0, 0);
      }
    }
  }
  // publish row denominators (col 0 of accd holds row-sums)
  if (cg == 0 && arow == 0) {
#pragma unroll
    for (int reg = 0; reg < 4; ++reg)
      d_lds[rg * 16 + (lane >> 4) * 4 + reg] = accd[reg];
  }
  __syncthreads();
  // epilogue: divide, ELU, store fp32
  const size_t ob = ((size_t)b * 2048 + i0 + rg * 16) * 256 + cg * 64;
#pragma unroll
  for (int reg = 0; reg < 4; ++reg) {
    int rr = (lane >> 4) * 4 + reg;
    float inv = 1.0f / d_lds[rg * 16 + rr];
#pragma unroll
    for (int ni = 0; ni < 4; ++ni) {
      int c = 16 * ni + arow;
      float v = acc[ni][reg] * inv;
      v = v > 0.f ? v : (__expf(v) - 1.f);
      out[ob + (size_t)rr * 256 + c] = v;
    }
  }
}

extern "C" void kernel_launch(void* const* d_in, const int* in_sizes, int n_in,
                              void* d_out, int out_size, void* d_ws, size_t ws_size,
                              hipStream_t stream) {
  (void)in_sizes; (void)n_in; (void)out_size; (void)ws_size;
  const float* h = (const float*)d_in[0];
  const float* W = (const float*)d_in[1];
  const float* a1 = (const float*)d_in[2];
  const float* a2 = (const float*)d_in[3];
  float* out = (float*)d_out;
  char* ws = (char*)d_ws;
  _Float16* WhT = (_Float16*)(ws);             // 8*256*2048*2 = 8388608 B (pre-swizzled)
  _Float16* W16 = (_Float16*)(ws + 8388608);   // 262144 B (pre-swizzled)
  float* u1 = (float*)(ws + 8650752);          // 2048 B
  float* u2 = (float*)(ws + 8652800);          // 2048 B
  float* s1 = (float*)(ws + 8654848);          // 65536 B
  float* s2 = (float*)(ws + 8720384);          // 65536 B

  hipLaunchKernelGGL(k_convW, dim3(128), dim3(256), 0, stream, W, W16);
  hipLaunchKernelGGL(k_uvec, dim3(8), dim3(256), 0, stream, W, a1, a2, u1, u2);
  hipLaunchKernelGGL(k_gemm_wh, dim3(256), dim3(512), 0, stream, h, W16, u1, u2, s1, s2, WhT);
  hipLaunchKernelGGL(k_attn, dim3(256), dim3(1024), 0, stream, WhT, s1, s2, out);
}